// Round 6
// baseline (195.729 us; speedup 1.0000x reference)
//
#include <hip/hip_runtime.h>
#include <hip/hip_bf16.h>
#include <math.h>

#define S_LEN 1024
#define BATCH 4
#define HID 1024
#define NHEADS 16
#define DHEAD 64
#define NTOT 64
#define M_ROWS 4096

typedef unsigned short u16;
typedef unsigned int u32;
typedef __bf16 bf16x8 __attribute__((ext_vector_type(8)));
typedef float f32x4 __attribute__((ext_vector_type(4)));

__device__ __forceinline__ u16 f2bf(float x) {
    __hip_bfloat16 h = __float2bfloat16(x);
    return *(u16*)&h;
}

// async global->LDS, 16B/lane; LDS dest = wave-uniform base + lane*16
__device__ __forceinline__ void gll16(const u16* g, u16* l) {
    __builtin_amdgcn_global_load_lds(
        (const __attribute__((address_space(1))) u32*)g,
        (__attribute__((address_space(3))) u32*)l, 16, 0, 0);
}

// ---------------------------------------------------------------------------
// fused fp32 -> bf16 convert for X and the three W matrices
// ---------------------------------------------------------------------------
__global__ __launch_bounds__(256) void cvt_all(
    const float* __restrict__ X, const float* __restrict__ wq,
    const float* __restrict__ wk, const float* __restrict__ wv,
    u16* __restrict__ Xb, u16* __restrict__ Wb)
{
    const int bid = blockIdx.x;
    const float* src;
    u16* dst;
    size_t off;
    if (bid < 4096) {            // X: 4M elems
        src = X; dst = Xb; off = (size_t)bid * 1024;
    } else {                     // W: 3 x 1M elems
        const int wb = bid - 4096;
        const int which = wb >> 10;
        src = (which == 0) ? wq : (which == 1) ? wk : wv;
        dst = Wb + (size_t)which * HID * HID;
        off = (size_t)(wb & 1023) * 1024;
    }
    const size_t idx = off + threadIdx.x * 4;
    float4 x = *(const float4*)(src + idx);
    *(ushort4*)(dst + idx) = make_ushort4(f2bf(x.x), f2bf(x.y), f2bf(x.z), f2bf(x.w));
}

// ---------------------------------------------------------------------------
// QKV projection (m97-style, 128x128, BK=32, gll16).  Q,K -> [n][s][d] bf16;
// V -> V^T [n][d][s] bf16 directly.
// ---------------------------------------------------------------------------
__global__ __launch_bounds__(256, 3) void qkv_mfma(
    const u16* __restrict__ Xb, const u16* __restrict__ Wb,
    const float* __restrict__ bq, const float* __restrict__ bk,
    const float* __restrict__ bv,
    u16* __restrict__ Qb, u16* __restrict__ Kb, u16* __restrict__ VT)
{
    const int m0 = blockIdx.x * 128;
    const int n0 = blockIdx.y * 128;
    const int which = blockIdx.z;

    __shared__ __align__(16) u16 As[128 * 32];
    __shared__ __align__(16) u16 Bs[128 * 32];

    const int tid = threadIdx.x;
    const int lane = tid & 63;
    const int w = tid >> 6;
    const int wm = w & 1, wn = w >> 1;
    const int quad = lane >> 4;
    const int l15 = lane & 15;

    const u16* W = Wb + (size_t)which * HID * HID;

    f32x4 acc[4][4];
    #pragma unroll
    for (int i = 0; i < 4; ++i)
        #pragma unroll
        for (int j = 0; j < 4; ++j)
            #pragma unroll
            for (int r = 0; r < 4; ++r) acc[i][j][r] = 0.0f;

    const int lrow = lane >> 2, lchk = (lane & 3) * 8;

    for (int k0 = 0; k0 < HID; k0 += 32) {
        #pragma unroll
        for (int c = 0; c < 2; ++c) {
            const int seg = w * 2 + c;
            const int row = seg * 16 + lrow;
            gll16(Xb + (size_t)(m0 + row) * HID + k0 + lchk, As + seg * 512);
            gll16(W  + (size_t)(n0 + row) * HID + k0 + lchk, Bs + seg * 512);
        }
        __syncthreads();

        bf16x8 af[4], bf[4];
        #pragma unroll
        for (int i = 0; i < 4; ++i)
            af[i] = *(const bf16x8*)(As + (wm * 64 + i * 16 + l15) * 32 + quad * 8);
        #pragma unroll
        for (int j = 0; j < 4; ++j)
            bf[j] = *(const bf16x8*)(Bs + (wn * 64 + j * 16 + l15) * 32 + quad * 8);
        #pragma unroll
        for (int i = 0; i < 4; ++i)
            #pragma unroll
            for (int j = 0; j < 4; ++j)
                acc[i][j] = __builtin_amdgcn_mfma_f32_16x16x32_bf16(
                    af[i], bf[j], acc[i][j], 0, 0, 0);
        __syncthreads();
    }

    const float* bias = (which == 0) ? bq : (which == 1) ? bk : bv;
    #pragma unroll
    for (int j = 0; j < 4; ++j) {
        const int o = n0 + wn * 64 + j * 16 + l15;
        const float bias_v = bias[o];
        const int head = o >> 6, d = o & 63;
        #pragma unroll
        for (int i = 0; i < 4; ++i) {
            const int mbase = m0 + wm * 64 + i * 16 + quad * 4;
            const int s = mbase >> 2;
            #pragma unroll
            for (int r = 0; r < 4; ++r) {
                const int n = r * NHEADS + head;
                const u16 hv = f2bf(acc[i][j][r] + bias_v);
                if (which == 0)
                    Qb[((size_t)n * S_LEN + s) * DHEAD + d] = hv;
                else if (which == 1)
                    Kb[((size_t)n * S_LEN + s) * DHEAD + d] = hv;
                else
                    VT[(size_t)n * (DHEAD * S_LEN) + (size_t)d * S_LEN + s] = hv;
            }
        }
    }
}

// ---------------------------------------------------------------------------
// Flash attention, transposed-score formulation, NO K/V LDS staging.
// K/V fragments are read directly from global (L1/L2-resident: each block's
// working set is 16KB/tile, shared by its 4 waves; ~2MB per XCD).  The main
// loop has ZERO barriers: P is a same-wave LDS round-trip.
//   P^T = K·Q^T   (MFMA operand swap)  -> C-regs hold t along r
//   pack f32x4 -> ds_write_b64 into Ps[q][t]
//   O^T = V^T·P^T
// Fixed-max softmax exp(v-16); per-lane l accumulator (q = lane-fixed).
// Epilogue: un-transpose O via LDS overlay (aliases Ps), coalesced stores.
// ---------------------------------------------------------------------------
__global__ __launch_bounds__(256, 4) void attn_mfma(
    const u16* __restrict__ Qb, const u16* __restrict__ Kb,
    const u16* __restrict__ VT, const float* __restrict__ mask,
    float* __restrict__ out)
{
    const int n = blockIdx.y;
    const int s0 = blockIdx.x * 128;
    const int b = n >> 4, head = n & 15;

    __shared__ __align__(16) char smem[128 * 72 * 4];   // 36 KB
    float* Of = (float*)smem;          // [128][72] f32 (epilogue overlay)
    u16*   Ps = (u16*)smem;            // [128][72] bf16 (first 18 KB)

    const int tid = threadIdx.x;
    const int lane = tid & 63;
    const int w = tid >> 6;
    const int quad = lane >> 4;
    const int l15 = lane & 15;
    const size_t nbase = (size_t)n * S_LEN * DHEAD;

    // Q fragments in registers (used as MFMA B-operand: Q^T)
    bf16x8 qf[2][2];
    #pragma unroll
    for (int mi = 0; mi < 2; ++mi)
        #pragma unroll
        for (int st = 0; st < 2; ++st)
            qf[mi][st] = *(const bf16x8*)(Qb + nbase +
                (size_t)(s0 + w * 32 + mi * 16 + l15) * 64 + st * 32 + quad * 8);

    f32x4 O[2][4];          // O^T[d][q] accumulators
    float l_lane[2];
    #pragma unroll
    for (int mi = 0; mi < 2; ++mi) {
        l_lane[mi] = 0.0f;
        #pragma unroll
        for (int jt = 0; jt < 4; ++jt)
            #pragma unroll
            for (int r = 0; r < 4; ++r) O[mi][jt][r] = 0.0f;
    }

    // global fragment base offsets (per-lane)
    const u16* Kg = Kb + nbase;               // + (t0+j*16+l15)*64 + st*32+quad*8
    const u16* Vg = VT + nbase;               // + (jt*16+l15)*S_LEN + t0 + st*32+quad*8
    const float* mg = mask + (size_t)n * S_LEN;

    for (int it = 0; it < 16; ++it) {
        const int t0 = it * 64;

        // ---- P^T = K·Q^T ----
        f32x4 sc[2][4];
        #pragma unroll
        for (int mi = 0; mi < 2; ++mi)
            #pragma unroll
            for (int j = 0; j < 4; ++j)
                #pragma unroll
                for (int r = 0; r < 4; ++r) sc[mi][j][r] = 0.0f;

        #pragma unroll
        for (int st = 0; st < 2; ++st) {
            bf16x8 kf[4];
            #pragma unroll
            for (int j = 0; j < 4; ++j)
                kf[j] = *(const bf16x8*)(Kg + (size_t)(t0 + j * 16 + l15) * 64 +
                                         st * 32 + quad * 8);
            #pragma unroll
            for (int mi = 0; mi < 2; ++mi)
                #pragma unroll
                for (int j = 0; j < 4; ++j)
                    sc[mi][j] = __builtin_amdgcn_mfma_f32_16x16x32_bf16(
                        kf[j], qf[mi][st], sc[mi][j], 0, 0, 0);
        }

        // ---- softmax (fixed max) + packed P^T write ----
        float4 mv4[4];
        #pragma unroll
        for (int j = 0; j < 4; ++j)
            mv4[j] = *(const float4*)(mg + t0 + j * 16 + quad * 4);

        #pragma unroll
        for (int mi = 0; mi < 2; ++mi) {
            const int q = w * 32 + mi * 16 + l15;
            #pragma unroll
            for (int j = 0; j < 4; ++j) {
                const float p0 = __expf(fmaf(sc[mi][j][0], 0.125f, mv4[j].x - 16.0f));
                const float p1 = __expf(fmaf(sc[mi][j][1], 0.125f, mv4[j].y - 16.0f));
                const float p2 = __expf(fmaf(sc[mi][j][2], 0.125f, mv4[j].z - 16.0f));
                const float p3 = __expf(fmaf(sc[mi][j][3], 0.125f, mv4[j].w - 16.0f));
                l_lane[mi] += (p0 + p1) + (p2 + p3);
                *(ushort4*)(Ps + q * 72 + j * 16 + quad * 4) =
                    make_ushort4(f2bf(p0), f2bf(p1), f2bf(p2), f2bf(p3));
            }
        }
        // same-wave produce/consume of Ps rows -> no barrier

        // ---- O^T += V^T·P^T ----
        #pragma unroll
        for (int st = 0; st < 2; ++st) {
            bf16x8 vf[4];
            #pragma unroll
            for (int jt = 0; jt < 4; ++jt)
                vf[jt] = *(const bf16x8*)(Vg + (size_t)(jt * 16 + l15) * S_LEN +
                                          t0 + st * 32 + quad * 8);
            #pragma unroll
            for (int mi = 0; mi < 2; ++mi) {
                bf16x8 pf = *(const bf16x8*)(Ps + (w * 32 + mi * 16 + l15) * 72 +
                                             st * 32 + quad * 8);
                #pragma unroll
                for (int jt = 0; jt < 4; ++jt)
                    O[mi][jt] = __builtin_amdgcn_mfma_f32_16x16x32_bf16(
                        vf[jt], pf, O[mi][jt], 0, 0, 0);
            }
        }
    }

    // ---- epilogue ----
    float inv_l[2];
    #pragma unroll
    for (int mi = 0; mi < 2; ++mi) {
        float l = l_lane[mi];
        l += __shfl_xor(l, 16);
        l += __shfl_xor(l, 32);
        inv_l[mi] = 1.0f / l;
    }
    __syncthreads();   // all waves done with Ps before the Of overlay

    #pragma unroll
    for (int mi = 0; mi < 2; ++mi) {
        const int q = w * 32 + mi * 16 + l15;
        #pragma unroll
        for (int jt = 0; jt < 4; ++jt) {
            f32x4 v = O[mi][jt];
            float4 o4 = make_float4(v[0] * inv_l[mi], v[1] * inv_l[mi],
                                    v[2] * inv_l[mi], v[3] * inv_l[mi]);
            *(float4*)(Of + q * 72 + jt * 16 + quad * 4) = o4;
        }
    }
    __syncthreads();

    const int tx = tid & 15, ty = tid >> 4;
    #pragma unroll
    for (int p = 0; p < 8; ++p) {
        const int q = p * 16 + ty;
        float4 v = *(const float4*)(Of + q * 72 + tx * 4);
        *(float4*)(out + (size_t)(s0 + q) * (BATCH * HID) + (size_t)b * HID +
                   head * DHEAD + tx * 4) = v;
    }
}

extern "C" void kernel_launch(void* const* d_in, const int* in_sizes, int n_in,
                              void* d_out, int out_size, void* d_ws, size_t ws_size,
                              hipStream_t stream)
{
    const float* X    = (const float*)d_in[0];
    const float* mask = (const float*)d_in[1];
    const float* Wq   = (const float*)d_in[2];
    const float* bq   = (const float*)d_in[3];
    const float* Wk   = (const float*)d_in[4];
    const float* bk   = (const float*)d_in[5];
    const float* Wv   = (const float*)d_in[6];
    const float* bv   = (const float*)d_in[7];
    float* out = (float*)d_out;

    const size_t MX = (size_t)M_ROWS * HID;   // 4M elems
    const size_t MW = (size_t)HID * HID;      // 1M elems
    u16* wsp = (u16*)d_ws;
    u16* Xb = wsp;
    u16* Wb = Xb + MX;          // 3 matrices
    u16* Qb = Wb + 3 * MW;
    u16* Kb = Qb + MX;
    u16* VT = Kb + MX;          // total 19M u16 = 38 MB

    cvt_all<<<dim3(4096 + 3072), 256, 0, stream>>>(X, Wq, Wk, Wv, Xb, Wb);
    qkv_mfma<<<dim3(M_ROWS / 128, HID / 128, 3), 256, 0, stream>>>(
        Xb, Wb, bq, bk, bv, Qb, Kb, VT);
    attn_mfma<<<dim3(S_LEN / 128, NTOT), 256, 0, stream>>>(Qb, Kb, VT, mask, out);
}

// Round 7
// 165.410 us; speedup vs baseline: 1.1833x; 1.1833x over previous
//
#include <hip/hip_runtime.h>
#include <hip/hip_bf16.h>
#include <math.h>

#define S_LEN 1024
#define BATCH 4
#define HID 1024
#define NHEADS 16
#define DHEAD 64
#define NTOT 64
#define M_ROWS 4096

typedef unsigned short u16;
typedef unsigned int u32;
typedef __bf16 bf16x8 __attribute__((ext_vector_type(8)));
typedef float f32x4 __attribute__((ext_vector_type(4)));

__device__ __forceinline__ u16 f2bf(float x) {
    __hip_bfloat16 h = __float2bfloat16(x);
    return *(u16*)&h;
}

// async global->LDS, 16B/lane; LDS dest = wave-uniform base + lane*16
__device__ __forceinline__ void gll16(const u16* g, u16* l) {
    __builtin_amdgcn_global_load_lds(
        (const __attribute__((address_space(1))) u32*)g,
        (__attribute__((address_space(3))) u32*)l, 16, 0, 0);
}

// ---------------------------------------------------------------------------
// Fragment-major layouts (per head-batch n, 64K u16 each):
//   K/Q:  [n][it(16)][st(2)][j(4)][quad(4)][l15(16)][e(8)]
//         element (row = it*64 + j*16 + l15, d = st*32 + quad*8 + e)
//   V:    [n][it(16)][st(2)][d(64)][quad(4)][e(8)]
//         element (d, t = it*64 + st*32 + quad*8 + e)
// -> every attn frag read = base + lane*16B, one coalesced 1KB dwordx4.
// ---------------------------------------------------------------------------
__device__ __forceinline__ size_t kq_idx(int n, int row, int d) {
    const int it = row >> 6, jj = (row >> 4) & 3, l = row & 15;
    const int st = d >> 5, qd = (d >> 3) & 3, e = d & 7;
    return (((((((size_t)n * 16 + it) * 2 + st) * 4 + jj) * 4 + qd) * 16) + l) * 8 + e;
}
__device__ __forceinline__ size_t v_idx(int n, int d, int t) {
    const int it = t >> 6, st = (t >> 5) & 1, qd = (t >> 3) & 3, e = t & 7;
    return ((((size_t)n * 16 + it) * 2 + st) * 64 + d) * 32 + qd * 8 + e;
}

// ---------------------------------------------------------------------------
// fused fp32 -> bf16 convert for X and the three W matrices
// ---------------------------------------------------------------------------
__global__ __launch_bounds__(256) void cvt_all(
    const float* __restrict__ X, const float* __restrict__ wq,
    const float* __restrict__ wk, const float* __restrict__ wv,
    u16* __restrict__ Xb, u16* __restrict__ Wb)
{
    const int bid = blockIdx.x;
    const float* src;
    u16* dst;
    size_t off;
    if (bid < 4096) {            // X: 4M elems
        src = X; dst = Xb; off = (size_t)bid * 1024;
    } else {                     // W: 3 x 1M elems
        const int wb = bid - 4096;
        const int which = wb >> 10;
        src = (which == 0) ? wq : (which == 1) ? wk : wv;
        dst = Wb + (size_t)which * HID * HID;
        off = (size_t)(wb & 1023) * 1024;
    }
    const size_t idx = off + threadIdx.x * 4;
    float4 x = *(const float4*)(src + idx);
    *(ushort4*)(dst + idx) = make_ushort4(f2bf(x.x), f2bf(x.y), f2bf(x.z), f2bf(x.w));
}

// ---------------------------------------------------------------------------
// QKV projection (m97-style, 128x128, BK=32, gll16).  Outputs written in
// fragment-major layouts above.
// ---------------------------------------------------------------------------
__global__ __launch_bounds__(256, 3) void qkv_mfma(
    const u16* __restrict__ Xb, const u16* __restrict__ Wb,
    const float* __restrict__ bq, const float* __restrict__ bk,
    const float* __restrict__ bv,
    u16* __restrict__ Qf, u16* __restrict__ Kf, u16* __restrict__ Vf)
{
    const int m0 = blockIdx.x * 128;
    const int n0 = blockIdx.y * 128;
    const int which = blockIdx.z;

    __shared__ __align__(16) u16 As[128 * 32];
    __shared__ __align__(16) u16 Bs[128 * 32];

    const int tid = threadIdx.x;
    const int lane = tid & 63;
    const int w = tid >> 6;
    const int wm = w & 1, wn = w >> 1;
    const int quad = lane >> 4;
    const int l15 = lane & 15;

    const u16* W = Wb + (size_t)which * HID * HID;

    f32x4 acc[4][4];
    #pragma unroll
    for (int i = 0; i < 4; ++i)
        #pragma unroll
        for (int j = 0; j < 4; ++j)
            #pragma unroll
            for (int r = 0; r < 4; ++r) acc[i][j][r] = 0.0f;

    const int lrow = lane >> 2, lchk = (lane & 3) * 8;

    for (int k0 = 0; k0 < HID; k0 += 32) {
        #pragma unroll
        for (int c = 0; c < 2; ++c) {
            const int seg = w * 2 + c;
            const int row = seg * 16 + lrow;
            gll16(Xb + (size_t)(m0 + row) * HID + k0 + lchk, As + seg * 512);
            gll16(W  + (size_t)(n0 + row) * HID + k0 + lchk, Bs + seg * 512);
        }
        __syncthreads();

        bf16x8 af[4], bf[4];
        #pragma unroll
        for (int i = 0; i < 4; ++i)
            af[i] = *(const bf16x8*)(As + (wm * 64 + i * 16 + l15) * 32 + quad * 8);
        #pragma unroll
        for (int j = 0; j < 4; ++j)
            bf[j] = *(const bf16x8*)(Bs + (wn * 64 + j * 16 + l15) * 32 + quad * 8);
        #pragma unroll
        for (int i = 0; i < 4; ++i)
            #pragma unroll
            for (int j = 0; j < 4; ++j)
                acc[i][j] = __builtin_amdgcn_mfma_f32_16x16x32_bf16(
                    af[i], bf[j], acc[i][j], 0, 0, 0);
        __syncthreads();
    }

    const float* bias = (which == 0) ? bq : (which == 1) ? bk : bv;
    #pragma unroll
    for (int j = 0; j < 4; ++j) {
        const int o = n0 + wn * 64 + j * 16 + l15;
        const float bias_v = bias[o];
        const int head = o >> 6, d = o & 63;
        #pragma unroll
        for (int i = 0; i < 4; ++i) {
            const int mbase = m0 + wm * 64 + i * 16 + quad * 4;
            const int s = mbase >> 2;
            #pragma unroll
            for (int r = 0; r < 4; ++r) {
                const int n = r * NHEADS + head;
                const u16 hv = f2bf(acc[i][j][r] + bias_v);
                if (which == 0)
                    Qf[kq_idx(n, s, d)] = hv;
                else if (which == 1)
                    Kf[kq_idx(n, s, d)] = hv;
                else
                    Vf[v_idx(n, d, s)] = hv;
            }
        }
    }
}

// ---------------------------------------------------------------------------
// Flash attention: zero-barrier main loop, K/V frags read directly from
// global in fragment-major layout (coalesced 1KB loads), register
// double-buffer prefetch one tile ahead.  Grid = (head n, q-tile) so all
// q-tiles of a head share one XCD's L2.
//   P^T = K·Q^T  ->  pack f32x4 -> ds_write_b64  ->  O^T = V^T·P^T
// Fixed-max softmax exp(v-16); per-lane l accumulator.
// ---------------------------------------------------------------------------
__device__ __forceinline__ void load_kv(
    const u16* __restrict__ Kg, const u16* __restrict__ Vg, int it,
    int lane8, int voff, bf16x8 kd[2][4], bf16x8 vd[2][4])
{
    #pragma unroll
    for (int st = 0; st < 2; ++st)
        #pragma unroll
        for (int j = 0; j < 4; ++j) {
            kd[st][j] = *(const bf16x8*)(Kg + ((it * 2 + st) * 4 + j) * 512 + lane8);
            vd[st][j] = *(const bf16x8*)(Vg + (it * 2 + st) * 2048 + j * 512 + voff);
        }
}

__global__ __launch_bounds__(256, 2) void attn_mfma(
    const u16* __restrict__ Qf, const u16* __restrict__ Kf,
    const u16* __restrict__ Vf, const float* __restrict__ mask,
    float* __restrict__ out)
{
    const int n  = blockIdx.x;         // head-batch: fixes XCD = n%8
    const int s0 = blockIdx.y * 128;   // q tile
    const int b = n >> 4, head = n & 15;

    __shared__ __align__(16) char smem[128 * 72 * 4];   // 36 KB
    float* Of = (float*)smem;          // [128][72] f32 (epilogue overlay)
    u16*   Ps = (u16*)smem;            // [128][72] bf16

    const int tid = threadIdx.x;
    const int lane = tid & 63;
    const int w = tid >> 6;
    const int quad = lane >> 4;
    const int l15 = lane & 15;

    const u16* Qg = Qf + (size_t)n * 65536;
    const u16* Kg = Kf + (size_t)n * 65536;
    const u16* Vg = Vf + (size_t)n * 65536;
    const float* mg = mask + (size_t)n * S_LEN;

    const int lane8 = lane * 8;              // K/Q frag lane offset (u16)
    const int voff  = l15 * 32 + quad * 8;   // V frag lane offset (u16)

    // Q fragments (B-operand, Q^T), coalesced 1KB reads
    bf16x8 qf[2][2];
    {
        const int iq = (s0 >> 6) + (w >> 1);
        #pragma unroll
        for (int mi = 0; mi < 2; ++mi) {
            const int j = (w & 1) * 2 + mi;
            #pragma unroll
            for (int st = 0; st < 2; ++st)
                qf[mi][st] = *(const bf16x8*)(
                    Qg + ((iq * 2 + st) * 4 + j) * 512 + lane8);
        }
    }

    f32x4 O[2][4];
    float l_lane[2];
    #pragma unroll
    for (int mi = 0; mi < 2; ++mi) {
        l_lane[mi] = 0.0f;
        #pragma unroll
        for (int jt = 0; jt < 4; ++jt)
            #pragma unroll
            for (int r = 0; r < 4; ++r) O[mi][jt][r] = 0.0f;
    }

    // register double buffer for K/V fragments
    bf16x8 kb[2][2][4], vb[2][2][4];
    load_kv(Kg, Vg, 0, lane8, voff, kb[0], vb[0]);

    #pragma unroll 2
    for (int it = 0; it < 16; ++it) {
        const int cur = it & 1, nxt = cur ^ 1;
        if (it < 15)
            load_kv(Kg, Vg, it + 1, lane8, voff, kb[nxt], vb[nxt]);

        // ---- P^T = K·Q^T ----
        f32x4 sc[2][4];
        #pragma unroll
        for (int mi = 0; mi < 2; ++mi)
            #pragma unroll
            for (int j = 0; j < 4; ++j)
                #pragma unroll
                for (int r = 0; r < 4; ++r) sc[mi][j][r] = 0.0f;

        #pragma unroll
        for (int st = 0; st < 2; ++st)
            #pragma unroll
            for (int mi = 0; mi < 2; ++mi)
                #pragma unroll
                for (int j = 0; j < 4; ++j)
                    sc[mi][j] = __builtin_amdgcn_mfma_f32_16x16x32_bf16(
                        kb[cur][st][j], qf[mi][st], sc[mi][j], 0, 0, 0);

        // ---- softmax (fixed max) + packed P^T write ----
        const int t0 = it * 64;
        float4 mv4[4];
        #pragma unroll
        for (int j = 0; j < 4; ++j)
            mv4[j] = *(const float4*)(mg + t0 + j * 16 + quad * 4);

        #pragma unroll
        for (int mi = 0; mi < 2; ++mi) {
            const int q = w * 32 + mi * 16 + l15;
            #pragma unroll
            for (int j = 0; j < 4; ++j) {
                const float p0 = __expf(fmaf(sc[mi][j][0], 0.125f, mv4[j].x - 16.0f));
                const float p1 = __expf(fmaf(sc[mi][j][1], 0.125f, mv4[j].y - 16.0f));
                const float p2 = __expf(fmaf(sc[mi][j][2], 0.125f, mv4[j].z - 16.0f));
                const float p3 = __expf(fmaf(sc[mi][j][3], 0.125f, mv4[j].w - 16.0f));
                l_lane[mi] += (p0 + p1) + (p2 + p3);
                *(ushort4*)(Ps + q * 72 + j * 16 + quad * 4) =
                    make_ushort4(f2bf(p0), f2bf(p1), f2bf(p2), f2bf(p3));
            }
        }
        // same-wave produce/consume of Ps rows -> no barrier

        // ---- O^T += V^T·P^T ----
        #pragma unroll
        for (int st = 0; st < 2; ++st)
            #pragma unroll
            for (int mi = 0; mi < 2; ++mi) {
                bf16x8 pf = *(const bf16x8*)(Ps + (w * 32 + mi * 16 + l15) * 72 +
                                             st * 32 + quad * 8);
                #pragma unroll
                for (int jt = 0; jt < 4; ++jt)
                    O[mi][jt] = __builtin_amdgcn_mfma_f32_16x16x32_bf16(
                        vb[cur][st][jt], pf, O[mi][jt], 0, 0, 0);
            }
    }

    // ---- epilogue ----
    float inv_l[2];
    #pragma unroll
    for (int mi = 0; mi < 2; ++mi) {
        float l = l_lane[mi];
        l += __shfl_xor(l, 16);
        l += __shfl_xor(l, 32);
        inv_l[mi] = 1.0f / l;
    }
    __syncthreads();   // all waves done with Ps before the Of overlay

    #pragma unroll
    for (int mi = 0; mi < 2; ++mi) {
        const int q = w * 32 + mi * 16 + l15;
        #pragma unroll
        for (int jt = 0; jt < 4; ++jt) {
            f32x4 v = O[mi][jt];
            float4 o4 = make_float4(v[0] * inv_l[mi], v[1] * inv_l[mi],
                                    v[2] * inv_l[mi], v[3] * inv_l[mi]);
            *(float4*)(Of + q * 72 + jt * 16 + quad * 4) = o4;
        }
    }
    __syncthreads();

    const int tx = tid & 15, ty = tid >> 4;
    #pragma unroll
    for (int p = 0; p < 8; ++p) {
        const int q = p * 16 + ty;
        float4 v = *(const float4*)(Of + q * 72 + tx * 4);
        *(float4*)(out + (size_t)(s0 + q) * (BATCH * HID) + (size_t)b * HID +
                   head * DHEAD + tx * 4) = v;
    }
}

extern "C" void kernel_launch(void* const* d_in, const int* in_sizes, int n_in,
                              void* d_out, int out_size, void* d_ws, size_t ws_size,
                              hipStream_t stream)
{
    const float* X    = (const float*)d_in[0];
    const float* mask = (const float*)d_in[1];
    const float* Wq   = (const float*)d_in[2];
    const float* bq   = (const float*)d_in[3];
    const float* Wk   = (const float*)d_in[4];
    const float* bk   = (const float*)d_in[5];
    const float* Wv   = (const float*)d_in[6];
    const float* bv   = (const float*)d_in[7];
    float* out = (float*)d_out;

    const size_t MX = (size_t)M_ROWS * HID;   // 4M elems
    const size_t MW = (size_t)HID * HID;      // 1M elems
    u16* wsp = (u16*)d_ws;
    u16* Xb = wsp;
    u16* Wb = Xb + MX;          // 3 matrices
    u16* Qf = Wb + 3 * MW;
    u16* Kf = Qf + MX;
    u16* Vf = Kf + MX;          // total 19M u16 = 38 MB

    cvt_all<<<dim3(4096 + 3072), 256, 0, stream>>>(X, Wq, Wk, Wv, Xb, Wb);
    qkv_mfma<<<dim3(M_ROWS / 128, HID / 128, 3), 256, 0, stream>>>(
        Xb, Wb, bq, bk, bv, Qf, Kf, Vf);
    attn_mfma<<<dim3(NTOT, S_LEN / 128), 256, 0, stream>>>(Qf, Kf, Vf, mask, out);
}